// Round 20
// baseline (209.148 us; speedup 1.0000x reference)
//
#include <hip/hip_runtime.h>
#include <hip/hip_bf16.h>

#define NN 50000
#define NE 1600000
#define NIN 256
#define HID 32
#define FOUT 128
#define OSTR 256
#define NSB ((NN + 255) / 256)      // 196 superbuckets of 256 nodes
#define CHUNK 4096
#define NCH ((NE + CHUNK - 1) / CHUNK)  // 391 chunks per view

static constexpr float EPS = 1e-12f;

// ---------- bf16 helpers (tables stored bf16, all math f32) ----------
__device__ __forceinline__ float b2f(unsigned short s) {
    return __uint_as_float((unsigned)s << 16);
}
__device__ __forceinline__ unsigned short f2b(float f) {
    unsigned u = __float_as_uint(f);
    u += 0x7FFFu + ((u >> 16) & 1u);   // round-to-nearest-even
    return (unsigned short)(u >> 16);
}
__device__ __forceinline__ unsigned pack2(float a, float b) {
    return (unsigned)f2b(a) | ((unsigned)f2b(b) << 16);
}

// ---------- pass 0: per-chunk histogram, stored (no atomics) ----------
__global__ __launch_bounds__(256) void k_hist(const int* __restrict__ dstA,
                                              const int* __restrict__ dstB,
                                              unsigned* __restrict__ hcA,
                                              unsigned* __restrict__ hcB, int half) {
    __shared__ unsigned h[NSB];
    for (int i = threadIdx.x; i < NSB; i += 256) h[i] = 0u;
    __syncthreads();
    bool sec = blockIdx.x >= half;
    int c = sec ? blockIdx.x - half : blockIdx.x;
    const int* dst = sec ? dstB : dstA;
    unsigned* hc = sec ? hcB : hcA;
    int beg = c * CHUNK, end = min(beg + CHUNK, NE);
    for (int e = beg + (int)threadIdx.x; e < end; e += 256)
        atomicAdd(&h[dst[e] >> 8], 1u);
    __syncthreads();
    for (int i = threadIdx.x; i < NSB; i += 256) hc[(size_t)c * NSB + i] = h[i];
}

// ---------- per-bucket scan over chunks ----------
__global__ __launch_bounds__(256) void k_cscan(unsigned* __restrict__ hcA,
                                               unsigned* __restrict__ hcB,
                                               unsigned* __restrict__ totA,
                                               unsigned* __restrict__ totB, int half) {
    __shared__ unsigned tile[256];
    __shared__ unsigned carry;
    bool sec = blockIdx.x >= half;
    int sb = sec ? blockIdx.x - half : blockIdx.x;
    unsigned* hc = sec ? hcB : hcA;
    unsigned* tot = sec ? totB : totA;
    if (threadIdx.x == 0) carry = 0u;
    __syncthreads();
    for (int base = 0; base < NCH; base += 256) {
        int c = base + (int)threadIdx.x;
        unsigned v = (c < NCH) ? hc[(size_t)c * NSB + sb] : 0u;
        tile[threadIdx.x] = v;
        __syncthreads();
        for (int off = 1; off < 256; off <<= 1) {
            unsigned t = (threadIdx.x >= (unsigned)off) ? tile[threadIdx.x - off] : 0u;
            __syncthreads();
            tile[threadIdx.x] += t;
            __syncthreads();
        }
        if (c < NCH) hc[(size_t)c * NSB + sb] = carry + tile[threadIdx.x] - v;
        __syncthreads();
        if (threadIdx.x == 0) carry += tile[255];
        __syncthreads();
    }
    if (threadIdx.x == 0) tot[sb] = carry;
}

// ---------- bucket bases ----------
__global__ __launch_bounds__(256) void k_bscan(const unsigned* __restrict__ totA,
                                               const unsigned* __restrict__ totB,
                                               int* __restrict__ bbA, int* __restrict__ bbB) {
    __shared__ unsigned tile[256];
    const unsigned* tot = blockIdx.x ? totB : totA;
    int* bb = blockIdx.x ? bbB : bbA;
    unsigned v = (threadIdx.x < NSB) ? tot[threadIdx.x] : 0u;
    tile[threadIdx.x] = v;
    __syncthreads();
    for (int off = 1; off < 256; off <<= 1) {
        unsigned t = (threadIdx.x >= (unsigned)off) ? tile[threadIdx.x - off] : 0u;
        __syncthreads();
        tile[threadIdx.x] += t;
        __syncthreads();
    }
    if (threadIdx.x < NSB) bb[threadIdx.x] = (int)(tile[threadIdx.x] - v);
    if (threadIdx.x == 0) bb[NSB] = NE;
}

// ---------- pass 1: LDS counting-sort per chunk, ordered coalesced flush ----------
__global__ __launch_bounds__(256) void k_bin1(const int* __restrict__ srcA,
                                              const int* __restrict__ dstA,
                                              const unsigned* __restrict__ hcA,
                                              const int* __restrict__ bbA,
                                              int* __restrict__ tmpA,
                                              const int* __restrict__ srcB,
                                              const int* __restrict__ dstB,
                                              const unsigned* __restrict__ hcB,
                                              const int* __restrict__ bbB,
                                              int* __restrict__ tmpB, int half) {
    __shared__ unsigned hbase[NSB];
    __shared__ unsigned hcur[NSB];
    __shared__ unsigned hscan[NSB];
    __shared__ unsigned tile[256];
    __shared__ unsigned pay[CHUNK];
    __shared__ unsigned gpos[CHUNK];
    bool sec = blockIdx.x >= half;
    int c = sec ? blockIdx.x - half : blockIdx.x;
    const int* src = sec ? srcB : srcA;
    const int* dst = sec ? dstB : dstA;
    const unsigned* hc = sec ? hcB : hcA;
    const int* bb = sec ? bbB : bbA;
    int* tmp = sec ? tmpB : tmpA;
    for (int i = threadIdx.x; i < NSB; i += 256) {
        hbase[i] = (unsigned)bb[i] + hc[(size_t)c * NSB + i];
        hcur[i] = 0u;
    }
    __syncthreads();
    int beg = c * CHUNK;
    int len = min(CHUNK, NE - beg);
    int d[16], s[16];
#pragma unroll
    for (int j = 0; j < 16; ++j) {
        int idx = j * 256 + (int)threadIdx.x;
        if (idx < len) { d[j] = dst[beg + idx]; s[j] = src[beg + idx]; }
        else d[j] = -1;
    }
#pragma unroll
    for (int j = 0; j < 16; ++j)
        if (d[j] >= 0) atomicAdd(&hcur[d[j] >> 8], 1u);
    __syncthreads();
    unsigned v = (threadIdx.x < NSB) ? hcur[threadIdx.x] : 0u;
    tile[threadIdx.x] = v;
    __syncthreads();
    for (int off = 1; off < 256; off <<= 1) {
        unsigned t = (threadIdx.x >= (unsigned)off) ? tile[threadIdx.x - off] : 0u;
        __syncthreads();
        tile[threadIdx.x] += t;
        __syncthreads();
    }
    if (threadIdx.x < NSB) {
        unsigned excl = tile[threadIdx.x] - v;
        hscan[threadIdx.x] = excl;
        hcur[threadIdx.x] = excl;
    }
    __syncthreads();
#pragma unroll
    for (int j = 0; j < 16; ++j) {
        if (d[j] >= 0) {
            int sb = d[j] >> 8;
            unsigned p = atomicAdd(&hcur[sb], 1u);
            pay[p] = ((unsigned)(d[j] & 255) << 16) | (unsigned)s[j];
            gpos[p] = hbase[sb] + (p - hscan[sb]);
        }
    }
    __syncthreads();
    for (int i = threadIdx.x; i < len; i += 256)
        tmp[gpos[i]] = (int)pay[i];
}

// ---------- pass 2: per-superbucket fine scatter + deg/rowptr/dinv ----------
__global__ __launch_bounds__(256) void k_bin2(const int* __restrict__ tmpA,
                                              const int* __restrict__ bbA,
                                              unsigned short* __restrict__ csrA,
                                              unsigned* __restrict__ degA,
                                              float* __restrict__ dinvA,
                                              int* __restrict__ rpA,
                                              const int* __restrict__ tmpB,
                                              const int* __restrict__ bbB,
                                              unsigned short* __restrict__ csrB,
                                              unsigned* __restrict__ degB,
                                              float* __restrict__ dinvB,
                                              int* __restrict__ rpB, int half) {
    __shared__ unsigned cnt[256];
    __shared__ unsigned scan[256];
    __shared__ unsigned curs[256];
    bool sec = blockIdx.x >= half;
    int sb = sec ? blockIdx.x - half : blockIdx.x;
    const int* tmp = sec ? tmpB : tmpA;
    const int* bb = sec ? bbB : bbA;
    unsigned short* csr = sec ? csrB : csrA;
    unsigned* deg = sec ? degB : degA;
    float* dinv = sec ? dinvB : dinvA;
    int* rp = sec ? rpB : rpA;
    int beg = bb[sb], end = bb[sb + 1];
    cnt[threadIdx.x] = 0u;
    __syncthreads();
    for (int e = beg + (int)threadIdx.x; e < end; e += 256)
        atomicAdd(&cnt[(tmp[e] >> 16) & 255], 1u);
    __syncthreads();
    unsigned v = cnt[threadIdx.x];
    scan[threadIdx.x] = v;
    __syncthreads();
    for (int off = 1; off < 256; off <<= 1) {
        unsigned t = (threadIdx.x >= (unsigned)off) ? scan[threadIdx.x - off] : 0u;
        __syncthreads();
        scan[threadIdx.x] += t;
        __syncthreads();
    }
    unsigned excl = scan[threadIdx.x] - v;
    int n = sb * 256 + (int)threadIdx.x;
    if (n < NN) {
        deg[n] = v;
        rp[n] = beg + (int)excl;
        dinv[n] = rsqrtf((float)(v + 1u));
    }
    curs[threadIdx.x] = (unsigned)beg + excl;
    __syncthreads();
    for (int e = beg + (int)threadIdx.x; e < end; e += 256) {
        int p = tmp[e];
        unsigned pos = atomicAdd(&curs[(p >> 16) & 255], 1u);
        csr[pos] = (unsigned short)(p & 0xFFFF);
    }
}

// ---------- layer-1 GEMM: 8 waves = (col-slice x k-half), row-per-lane, scalar W ----------
__global__ __launch_bounds__(512) void k_gemm_in(const float* __restrict__ x,
                                                 const float* __restrict__ W,
                                                 const float* __restrict__ dinvU,
                                                 const float* __restrict__ dinvV,
                                                 unsigned short* __restrict__ hU,
                                                 unsigned short* __restrict__ hV, int N) {
    __shared__ float part[4][64][9];   // [col-slice wave][row lane][8 cols], pad 9
    int t = threadIdx.x;
    int lane = t & 63;
    int w = t >> 6;                                       // 0..7
    int ws = __builtin_amdgcn_readfirstlane(w & 3);       // col-slice
    int kh = __builtin_amdgcn_readfirstlane(w >> 2);      // k-half
    int c0 = ws * 8;
    int row = blockIdx.x * 64 + lane;
    float acc[8];
#pragma unroll
    for (int j = 0; j < 8; ++j) acc[j] = 0.f;
    if (row < N) {
        const float4* xr = reinterpret_cast<const float4*>(x + (size_t)row * NIN) + kh * 32;
        const float* Wb = W + (kh * 128) * HID + c0;
#pragma unroll 4
        for (int i = 0; i < 32; ++i) {     // uniform i, kh, c0 -> scalar W loads
            float4 v = xr[i];
            const float* Wk = Wb + (i * 4) * HID;
#pragma unroll
            for (int j = 0; j < 8; ++j) {
                acc[j] = fmaf(v.x, Wk[j], acc[j]);
                acc[j] = fmaf(v.y, Wk[HID + j], acc[j]);
                acc[j] = fmaf(v.z, Wk[2 * HID + j], acc[j]);
                acc[j] = fmaf(v.w, Wk[3 * HID + j], acc[j]);
            }
        }
    }
    if (kh == 1) {
#pragma unroll
        for (int j = 0; j < 8; ++j) part[ws][lane][j] = acc[j];
    }
    __syncthreads();
    if (kh == 1 || row >= N) return;
#pragma unroll
    for (int j = 0; j < 8; ++j) acc[j] += part[ws][lane][j];
    float du = dinvU[row], dw = dinvV[row];
    uint4 wu, wvv;
    wu.x = pack2(acc[0] * du, acc[1] * du); wu.y = pack2(acc[2] * du, acc[3] * du);
    wu.z = pack2(acc[4] * du, acc[5] * du); wu.w = pack2(acc[6] * du, acc[7] * du);
    wvv.x = pack2(acc[0] * dw, acc[1] * dw); wvv.y = pack2(acc[2] * dw, acc[3] * dw);
    wvv.z = pack2(acc[4] * dw, acc[5] * dw); wvv.w = pack2(acc[6] * dw, acc[7] * dw);
    *reinterpret_cast<uint4*>(hU + (size_t)row * HID + c0) = wu;
    *reinterpret_cast<uint4*>(hV + (size_t)row * HID + c0) = wvv;
}

// ---------- unified pair pull: bf16 gather-sum, unroll-8, dual acc chains ----------
__device__ __forceinline__ void pull_sum(const unsigned short* __restrict__ t,
                                         const unsigned short* __restrict__ csr,
                                         const int* __restrict__ rowptr,
                                         const unsigned* __restrict__ deg,
                                         float* __restrict__ out, int blk, int tid) {
    int node = blk * 32 + tid / 8;
    int q = tid % 8;
    if (node >= NN) return;
    const ushort4* h4 = reinterpret_cast<const ushort4*>(t);
    int beg = rowptr[node];
    int end = beg + (int)deg[node];
    ushort4 sv = h4[(size_t)node * 8 + q];
    float4 acc0, acc1;
    acc0.x = b2f(sv.x); acc0.y = b2f(sv.y); acc0.z = b2f(sv.z); acc0.w = b2f(sv.w);
    acc1.x = 0.f; acc1.y = 0.f; acc1.z = 0.f; acc1.w = 0.f;
    int e = beg;
    for (; e + 8 <= end; e += 8) {
        int s0 = csr[e],     s1 = csr[e + 1], s2 = csr[e + 2], s3 = csr[e + 3];
        int s4 = csr[e + 4], s5 = csr[e + 5], s6 = csr[e + 6], s7 = csr[e + 7];
        ushort4 v0 = h4[(size_t)s0 * 8 + q];
        ushort4 v1 = h4[(size_t)s1 * 8 + q];
        ushort4 v2 = h4[(size_t)s2 * 8 + q];
        ushort4 v3 = h4[(size_t)s3 * 8 + q];
        ushort4 v4 = h4[(size_t)s4 * 8 + q];
        ushort4 v5 = h4[(size_t)s5 * 8 + q];
        ushort4 v6 = h4[(size_t)s6 * 8 + q];
        ushort4 v7 = h4[(size_t)s7 * 8 + q];
        acc0.x += (b2f(v0.x) + b2f(v1.x)) + (b2f(v2.x) + b2f(v3.x));
        acc0.y += (b2f(v0.y) + b2f(v1.y)) + (b2f(v2.y) + b2f(v3.y));
        acc0.z += (b2f(v0.z) + b2f(v1.z)) + (b2f(v2.z) + b2f(v3.z));
        acc0.w += (b2f(v0.w) + b2f(v1.w)) + (b2f(v2.w) + b2f(v3.w));
        acc1.x += (b2f(v4.x) + b2f(v5.x)) + (b2f(v6.x) + b2f(v7.x));
        acc1.y += (b2f(v4.y) + b2f(v5.y)) + (b2f(v6.y) + b2f(v7.y));
        acc1.z += (b2f(v4.z) + b2f(v5.z)) + (b2f(v6.z) + b2f(v7.z));
        acc1.w += (b2f(v4.w) + b2f(v5.w)) + (b2f(v6.w) + b2f(v7.w));
    }
    if (e + 4 <= end) {
        int s0 = csr[e], s1 = csr[e + 1], s2 = csr[e + 2], s3 = csr[e + 3];
        ushort4 v0 = h4[(size_t)s0 * 8 + q];
        ushort4 v1 = h4[(size_t)s1 * 8 + q];
        ushort4 v2 = h4[(size_t)s2 * 8 + q];
        ushort4 v3 = h4[(size_t)s3 * 8 + q];
        acc1.x += (b2f(v0.x) + b2f(v1.x)) + (b2f(v2.x) + b2f(v3.x));
        acc1.y += (b2f(v0.y) + b2f(v1.y)) + (b2f(v2.y) + b2f(v3.y));
        acc1.z += (b2f(v0.z) + b2f(v1.z)) + (b2f(v2.z) + b2f(v3.z));
        acc1.w += (b2f(v0.w) + b2f(v1.w)) + (b2f(v2.w) + b2f(v3.w));
        e += 4;
    }
    for (; e < end; ++e) {
        ushort4 v0 = h4[(size_t)csr[e] * 8 + q];
        acc0.x += b2f(v0.x); acc0.y += b2f(v0.y);
        acc0.z += b2f(v0.z); acc0.w += b2f(v0.w);
    }
    float4 acc;
    acc.x = acc0.x + acc1.x; acc.y = acc0.y + acc1.y;
    acc.z = acc0.z + acc1.z; acc.w = acc0.w + acc1.w;
    *reinterpret_cast<float4*>(out + (size_t)node * HID + q * 4) = acc;
}

__global__ __launch_bounds__(256) void k_pull_pair(
    const unsigned short* __restrict__ tA, const unsigned short* __restrict__ csrA,
    const int* __restrict__ rpA, const unsigned* __restrict__ degA, float* __restrict__ outA,
    const unsigned short* __restrict__ tB, const unsigned short* __restrict__ csrB,
    const int* __restrict__ rpB, const unsigned* __restrict__ degB, float* __restrict__ outB,
    int nblk) {
    int b = blockIdx.x;
    int xcd = b & 7;
    int blk = (b >> 3) * 4 + (xcd & 3);
    if (blk >= nblk) return;
    if (xcd >= 4) pull_sum(tB, csrB, rpB, degB, outB, blk, threadIdx.x);
    else          pull_sum(tA, csrA, rpA, degA, outA, blk, threadIdx.x);
}

// ---------- L1 mix: 8 lanes/node, shfl-group sim, bf16 T out ----------
__global__ __launch_bounds__(256) void k_mix1(const float* __restrict__ Su,
                                              const float* __restrict__ Sv,
                                              const float* __restrict__ dinvU,
                                              const float* __restrict__ dinvV,
                                              const float* __restrict__ bias,
                                              unsigned short* __restrict__ Tu,
                                              unsigned short* __restrict__ Tv) {
    int node = blockIdx.x * 32 + (threadIdx.x >> 3);
    int q = threadIdx.x & 7;
    if (node >= NN) return;
    float4 su = *reinterpret_cast<const float4*>(Su + (size_t)node * HID + 4 * q);
    float4 sv = *reinterpret_cast<const float4*>(Sv + (size_t)node * HID + 4 * q);
    float du = dinvU[node], dw = dinvV[node];
    float a0 = fmaf(su.x, du, bias[4 * q + 0]);
    float a1 = fmaf(su.y, du, bias[4 * q + 1]);
    float a2 = fmaf(su.z, du, bias[4 * q + 2]);
    float a3 = fmaf(su.w, du, bias[4 * q + 3]);
    float b0 = fmaf(sv.x, dw, bias[4 * q + 0]);
    float b1 = fmaf(sv.y, dw, bias[4 * q + 1]);
    float b2 = fmaf(sv.z, dw, bias[4 * q + 2]);
    float b3 = fmaf(sv.w, dw, bias[4 * q + 3]);
    float n1 = a0 * a0 + a1 * a1 + a2 * a2 + a3 * a3;
    float n2 = b0 * b0 + b1 * b1 + b2 * b2 + b3 * b3;
    float dt = a0 * b0 + a1 * b1 + a2 * b2 + a3 * b3;
#pragma unroll
    for (int m = 4; m >= 1; m >>= 1) {
        n1 += __shfl_xor(n1, m);
        n2 += __shfl_xor(n2, m);
        dt += __shfl_xor(dt, m);
    }
    float sim = dt / (fmaxf(sqrtf(n1), EPS) * fmaxf(sqrtf(n2), EPS));
    uint2 mu, mv;
    mu.x = pack2((a0 + b0 * sim) * du, (a1 + b1 * sim) * du);
    mu.y = pack2((a2 + b2 * sim) * du, (a3 + b3 * sim) * du);
    mv.x = pack2((b0 + a0 * sim) * dw, (b1 + a1 * sim) * dw);
    mv.y = pack2((b2 + a2 * sim) * dw, (b3 + a3 * sim) * dw);
    *reinterpret_cast<uint2*>(Tu + (size_t)node * HID + 4 * q) = mu;
    *reinterpret_cast<uint2*>(Tv + (size_t)node * HID + 4 * q) = mv;
}

// ---------- L2 epilogue: 8 lanes/node, LDS W + z, shfl sim, bf16 Pa/Pb ----------
__global__ __launch_bounds__(256) void k_hid_mix_pack(const float* __restrict__ Su,
                                                      const float* __restrict__ Sv,
                                                      const float* __restrict__ W,
                                                      const float* __restrict__ bias,
                                                      const float* __restrict__ dinvU,
                                                      const float* __restrict__ dinvV,
                                                      unsigned short* __restrict__ Pa,
                                                      unsigned short* __restrict__ Pb) {
    __shared__ float Ws[HID * HID];
    __shared__ float zu[32][33];
    __shared__ float zv[32][33];
    int t = threadIdx.x;
    for (int i = t; i < HID * HID; i += 256) Ws[i] = W[i];
    int nb = blockIdx.x * 32;
    int l = t >> 3, q = t & 7;
    int node = nb + l;
    {
        float4 fu = make_float4(0.f, 0.f, 0.f, 0.f), fv = fu;
        if (node < NN) {
            fu = *reinterpret_cast<const float4*>(Su + (size_t)node * HID + 4 * q);
            fv = *reinterpret_cast<const float4*>(Sv + (size_t)node * HID + 4 * q);
        }
        zu[l][4 * q + 0] = fu.x; zu[l][4 * q + 1] = fu.y;
        zu[l][4 * q + 2] = fu.z; zu[l][4 * q + 3] = fu.w;
        zv[l][4 * q + 0] = fv.x; zv[l][4 * q + 1] = fv.y;
        zv[l][4 * q + 2] = fv.z; zv[l][4 * q + 3] = fv.w;
    }
    __syncthreads();
    if (node >= NN) return;
    float a[4] = {0.f, 0.f, 0.f, 0.f};
    float b[4] = {0.f, 0.f, 0.f, 0.f};
#pragma unroll
    for (int k = 0; k < HID; ++k) {
        float zuk = zu[l][k], zvk = zv[l][k];
        const float* Wk = Ws + k * HID + 4 * q;
#pragma unroll
        for (int j = 0; j < 4; ++j) {
            a[j] = fmaf(zuk, Wk[j], a[j]);
            b[j] = fmaf(zvk, Wk[j], b[j]);
        }
    }
    float du = dinvU[node], dw = dinvV[node];
#pragma unroll
    for (int j = 0; j < 4; ++j) {
        a[j] = fmaf(a[j], du, bias[4 * q + j]);
        b[j] = fmaf(b[j], dw, bias[4 * q + j]);
    }
    float n1 = a[0]*a[0] + a[1]*a[1] + a[2]*a[2] + a[3]*a[3];
    float n2 = b[0]*b[0] + b[1]*b[1] + b[2]*b[2] + b[3]*b[3];
    float dt = a[0]*b[0] + a[1]*b[1] + a[2]*b[2] + a[3]*b[3];
#pragma unroll
    for (int m = 4; m >= 1; m >>= 1) {
        n1 += __shfl_xor(n1, m);
        n2 += __shfl_xor(n2, m);
        dt += __shfl_xor(dt, m);
    }
    float sim = dt / (fmaxf(sqrtf(n1), EPS) * fmaxf(sqrtf(n2), EPS));
    uint2 ma, mb;
    ma.x = pack2((a[0] + b[0] * sim) * du, (a[1] + b[1] * sim) * du);
    ma.y = pack2((a[2] + b[2] * sim) * du, (a[3] + b[3] * sim) * du);
    mb.x = pack2((b[0] + a[0] * sim) * du, (b[1] + a[1] * sim) * du);
    mb.y = pack2((b[2] + a[2] * sim) * du, (b[3] + a[3] * sim) * du);
    *reinterpret_cast<uint2*>(Pa + (size_t)node * HID + 4 * q) = ma;
    *reinterpret_cast<uint2*>(Pb + (size_t)node * HID + 4 * q) = mb;
}

// ---------- L3 GEMM: row-per-lane compute, LDS-staged coalesced stores ----------
__global__ __launch_bounds__(512) void k_gemm_out2(const float* __restrict__ Qa,
                                                   const float* __restrict__ Qb,
                                                   const float* __restrict__ dinvU,
                                                   const float* __restrict__ W,
                                                   const float* __restrict__ b,
                                                   float* __restrict__ out, int N) {
    __shared__ float ob[32 * 257];   // 32 rows/phase, pad 257 -> conflict-free
    int lane = threadIdx.x & 63;
    int wv = (int)(threadIdx.x >> 6);
    int view = __builtin_amdgcn_readfirstlane(wv >> 2);       // 0 or 1
    int c0 = __builtin_amdgcn_readfirstlane((wv & 3) * 32);   // col slice
    int row = blockIdx.x * 64 + lane;
    bool active = row < N;
    float a[32];
#pragma unroll
    for (int j = 0; j < 32; ++j) a[j] = 0.f;
    if (active) {
        const float* Q = view ? Qb : Qa;
        const float4* q4 = reinterpret_cast<const float4*>(Q + (size_t)row * HID);
#pragma unroll 2
        for (int k4 = 0; k4 < 8; ++k4) {
            float4 v = q4[k4];
            const float* Wk = W + (k4 * 4) * FOUT + c0;
#pragma unroll
            for (int j = 0; j < 32; ++j) {
                a[j] = fmaf(v.x, Wk[j], a[j]);
                a[j] = fmaf(v.y, Wk[FOUT + j], a[j]);
                a[j] = fmaf(v.z, Wk[2 * FOUT + j], a[j]);
                a[j] = fmaf(v.w, Wk[3 * FOUT + j], a[j]);
            }
        }
    }
    float du = active ? dinvU[row] : 0.f;
    int r32 = lane & 31;
    int hl = lane >> 5;
    for (int p = 0; p < 2; ++p) {
        if (hl == p) {
            int off = r32 * 257 + view * FOUT + c0;
#pragma unroll
            for (int j = 0; j < 32; ++j)
                ob[off + j] = fmaf(a[j], du, b[c0 + j]);
        }
        __syncthreads();
        int rbase = blockIdx.x * 64 + p * 32;
        int nrows = min(32, N - rbase);
        if (nrows > 0) {
            float* obase = out + (size_t)rbase * OSTR;
            int total = nrows * OSTR;
            for (int f = threadIdx.x; f < total; f += 512)
                obase[f] = ob[f + (f >> 8)];
        }
        __syncthreads();
    }
}

// ---------------- host ----------------
extern "C" void kernel_launch(void* const* d_in, const int* in_sizes, int n_in,
                              void* d_out, int out_size, void* d_ws, size_t ws_size,
                              hipStream_t stream) {
    const float* x     = (const float*)d_in[0];
    const int*   ei_u  = (const int*)d_in[1];
    const int*   ei_u2 = (const int*)d_in[2];
    const float* W_in  = (const float*)d_in[3];
    const float* b_in  = (const float*)d_in[4];
    const float* W_hid = (const float*)d_in[5];
    const float* b_hid = (const float*)d_in[6];
    const float* W_out = (const float*)d_in[7];
    const float* b_out = (const float*)d_in[8];
    float* out = (float*)d_out;

    const int* src_u  = ei_u;
    const int* dst_u  = ei_u + NE;
    const int* src_u2 = ei_u2;
    const int* dst_u2 = ei_u2 + NE;

    char* w = (char*)d_ws;
    auto carve = [&](size_t bytes) {
        char* p = w;
        w += (bytes + 255) & ~(size_t)255;
        return p;
    };
    unsigned* hc_u   = (unsigned*)carve((size_t)NCH * NSB * sizeof(unsigned));
    unsigned* hc_u2  = (unsigned*)carve((size_t)NCH * NSB * sizeof(unsigned));
    unsigned* tot_u  = (unsigned*)carve(NSB * sizeof(unsigned));
    unsigned* tot_u2 = (unsigned*)carve(NSB * sizeof(unsigned));
    int*      bb_u   = (int*)carve((NSB + 1) * sizeof(int));
    int*      bb_u2  = (int*)carve((NSB + 1) * sizeof(int));
    unsigned* deg_u  = (unsigned*)carve(NN * sizeof(unsigned));
    unsigned* deg_u2 = (unsigned*)carve(NN * sizeof(unsigned));
    float*    dinv_u  = (float*)carve(NN * sizeof(float));
    float*    dinv_u2 = (float*)carve(NN * sizeof(float));
    int*      rp_u   = (int*)carve(NN * sizeof(int));
    int*      rp_u2  = (int*)carve(NN * sizeof(int));
    unsigned short* csr_u  = (unsigned short*)carve((size_t)NE * sizeof(unsigned short));
    unsigned short* csr_u2 = (unsigned short*)carve((size_t)NE * sizeof(unsigned short));
    unsigned short* hU = (unsigned short*)carve((size_t)NN * HID * sizeof(unsigned short));
    unsigned short* hV = (unsigned short*)carve((size_t)NN * HID * sizeof(unsigned short));
    unsigned short* Tu = (unsigned short*)carve((size_t)NN * HID * sizeof(unsigned short));
    unsigned short* Tv = (unsigned short*)carve((size_t)NN * HID * sizeof(unsigned short));
    unsigned short* Pa = (unsigned short*)carve((size_t)NN * HID * sizeof(unsigned short));
    unsigned short* Pb = (unsigned short*)carve((size_t)NN * HID * sizeof(unsigned short));
    float* Su = (float*)carve((size_t)NN * HID * sizeof(float));
    float* Sv = (float*)carve((size_t)NN * HID * sizeof(float));
    // coarse-bin payload buffers alias Su/Sv (6.4 MB each; used only before layer 1)
    int* tmp_u  = (int*)Su;
    int* tmp_u2 = (int*)Sv;

    const int BLK = 256;
    const int gP32 = (NN + 31) / 32;        // 1563 blocks per view
    const int nPair = ((gP32 + 3) / 4) * 8; // XCD-partitioned pair grid = 3128
    const int gR64 = (NN + 63) / 64;        // 782

    // --- CSR build ---
    k_hist<<<2 * NCH, BLK, 0, stream>>>(dst_u, dst_u2, hc_u, hc_u2, NCH);
    k_cscan<<<2 * NSB, BLK, 0, stream>>>(hc_u, hc_u2, tot_u, tot_u2, NSB);
    k_bscan<<<2, BLK, 0, stream>>>(tot_u, tot_u2, bb_u, bb_u2);
    k_bin1<<<2 * NCH, BLK, 0, stream>>>(src_u, dst_u, hc_u, bb_u, tmp_u,
                                        src_u2, dst_u2, hc_u2, bb_u2, tmp_u2, NCH);
    k_bin2<<<2 * NSB, BLK, 0, stream>>>(tmp_u, bb_u, csr_u, deg_u, dinv_u, rp_u,
                                        tmp_u2, bb_u2, csr_u2, deg_u2, dinv_u2, rp_u2, NSB);

    // --- layer 1 ---
    k_gemm_in<<<gR64, 512, 0, stream>>>(x, W_in, dinv_u, dinv_u2, hU, hV, NN);
    k_pull_pair<<<nPair, BLK, 0, stream>>>(hU, csr_u, rp_u, deg_u, Su,
                                           hV, csr_u2, rp_u2, deg_u2, Sv, gP32);
    k_mix1<<<gP32, BLK, 0, stream>>>(Su, Sv, dinv_u, dinv_u2, b_in, Tu, Tv);

    // --- layer 2 (aggregate-then-GEMM) ---
    k_pull_pair<<<nPair, BLK, 0, stream>>>(Tu, csr_u, rp_u, deg_u, Su,
                                           Tv, csr_u2, rp_u2, deg_u2, Sv, gP32);
    k_hid_mix_pack<<<gP32, BLK, 0, stream>>>(Su, Sv, W_hid, b_hid, dinv_u, dinv_u2, Pa, Pb);

    // --- layer 3 (both branches on view u) ---
    k_pull_pair<<<nPair, BLK, 0, stream>>>(Pa, csr_u, rp_u, deg_u, Su,
                                           Pb, csr_u, rp_u, deg_u, Sv, gP32);
    k_gemm_out2<<<gR64, 512, 0, stream>>>(Su, Sv, dinv_u, W_out, b_out, out, NN);

    (void)in_sizes; (void)n_in; (void)out_size; (void)ws_size;
}

// Round 21
// 197.742 us; speedup vs baseline: 1.0577x; 1.0577x over previous
//
#include <hip/hip_runtime.h>
#include <hip/hip_bf16.h>

#define NN 50000
#define NE 1600000
#define NIN 256
#define HID 32
#define FOUT 128
#define OSTR 256
#define NSB ((NN + 255) / 256)      // 196 superbuckets of 256 nodes
#define CHUNK 4096
#define NCH ((NE + CHUNK - 1) / CHUNK)  // 391 chunks per view

static constexpr float EPS = 1e-12f;

// ---------- bf16 helpers (tables stored bf16, all math f32) ----------
__device__ __forceinline__ float b2f(unsigned short s) {
    return __uint_as_float((unsigned)s << 16);
}
__device__ __forceinline__ unsigned short f2b(float f) {
    unsigned u = __float_as_uint(f);
    u += 0x7FFFu + ((u >> 16) & 1u);   // round-to-nearest-even
    return (unsigned short)(u >> 16);
}
__device__ __forceinline__ unsigned pack2(float a, float b) {
    return (unsigned)f2b(a) | ((unsigned)f2b(b) << 16);
}

// ---------- pass 0: per-chunk histogram, stored (no atomics) ----------
__global__ __launch_bounds__(256) void k_hist(const int* __restrict__ dstA,
                                              const int* __restrict__ dstB,
                                              unsigned* __restrict__ hcA,
                                              unsigned* __restrict__ hcB, int half) {
    __shared__ unsigned h[NSB];
    for (int i = threadIdx.x; i < NSB; i += 256) h[i] = 0u;
    __syncthreads();
    bool sec = blockIdx.x >= half;
    int c = sec ? blockIdx.x - half : blockIdx.x;
    const int* dst = sec ? dstB : dstA;
    unsigned* hc = sec ? hcB : hcA;
    int beg = c * CHUNK, end = min(beg + CHUNK, NE);
    for (int e = beg + (int)threadIdx.x; e < end; e += 256)
        atomicAdd(&h[dst[e] >> 8], 1u);
    __syncthreads();
    for (int i = threadIdx.x; i < NSB; i += 256) hc[(size_t)c * NSB + i] = h[i];
}

// ---------- per-bucket scan over chunks ----------
__global__ __launch_bounds__(256) void k_cscan(unsigned* __restrict__ hcA,
                                               unsigned* __restrict__ hcB,
                                               unsigned* __restrict__ totA,
                                               unsigned* __restrict__ totB, int half) {
    __shared__ unsigned tile[256];
    __shared__ unsigned carry;
    bool sec = blockIdx.x >= half;
    int sb = sec ? blockIdx.x - half : blockIdx.x;
    unsigned* hc = sec ? hcB : hcA;
    unsigned* tot = sec ? totB : totA;
    if (threadIdx.x == 0) carry = 0u;
    __syncthreads();
    for (int base = 0; base < NCH; base += 256) {
        int c = base + (int)threadIdx.x;
        unsigned v = (c < NCH) ? hc[(size_t)c * NSB + sb] : 0u;
        tile[threadIdx.x] = v;
        __syncthreads();
        for (int off = 1; off < 256; off <<= 1) {
            unsigned t = (threadIdx.x >= (unsigned)off) ? tile[threadIdx.x - off] : 0u;
            __syncthreads();
            tile[threadIdx.x] += t;
            __syncthreads();
        }
        if (c < NCH) hc[(size_t)c * NSB + sb] = carry + tile[threadIdx.x] - v;
        __syncthreads();
        if (threadIdx.x == 0) carry += tile[255];
        __syncthreads();
    }
    if (threadIdx.x == 0) tot[sb] = carry;
}

// ---------- bucket bases ----------
__global__ __launch_bounds__(256) void k_bscan(const unsigned* __restrict__ totA,
                                               const unsigned* __restrict__ totB,
                                               int* __restrict__ bbA, int* __restrict__ bbB) {
    __shared__ unsigned tile[256];
    const unsigned* tot = blockIdx.x ? totB : totA;
    int* bb = blockIdx.x ? bbB : bbA;
    unsigned v = (threadIdx.x < NSB) ? tot[threadIdx.x] : 0u;
    tile[threadIdx.x] = v;
    __syncthreads();
    for (int off = 1; off < 256; off <<= 1) {
        unsigned t = (threadIdx.x >= (unsigned)off) ? tile[threadIdx.x - off] : 0u;
        __syncthreads();
        tile[threadIdx.x] += t;
        __syncthreads();
    }
    if (threadIdx.x < NSB) bb[threadIdx.x] = (int)(tile[threadIdx.x] - v);
    if (threadIdx.x == 0) bb[NSB] = NE;
}

// ---------- pass 1: LDS counting-sort per chunk, ordered coalesced flush ----------
__global__ __launch_bounds__(256) void k_bin1(const int* __restrict__ srcA,
                                              const int* __restrict__ dstA,
                                              const unsigned* __restrict__ hcA,
                                              const int* __restrict__ bbA,
                                              int* __restrict__ tmpA,
                                              const int* __restrict__ srcB,
                                              const int* __restrict__ dstB,
                                              const unsigned* __restrict__ hcB,
                                              const int* __restrict__ bbB,
                                              int* __restrict__ tmpB, int half) {
    __shared__ unsigned hbase[NSB];
    __shared__ unsigned hcur[NSB];
    __shared__ unsigned hscan[NSB];
    __shared__ unsigned tile[256];
    __shared__ unsigned pay[CHUNK];
    __shared__ unsigned gpos[CHUNK];
    bool sec = blockIdx.x >= half;
    int c = sec ? blockIdx.x - half : blockIdx.x;
    const int* src = sec ? srcB : srcA;
    const int* dst = sec ? dstB : dstA;
    const unsigned* hc = sec ? hcB : hcA;
    const int* bb = sec ? bbB : bbA;
    int* tmp = sec ? tmpB : tmpA;
    for (int i = threadIdx.x; i < NSB; i += 256) {
        hbase[i] = (unsigned)bb[i] + hc[(size_t)c * NSB + i];
        hcur[i] = 0u;
    }
    __syncthreads();
    int beg = c * CHUNK;
    int len = min(CHUNK, NE - beg);
    int d[16], s[16];
#pragma unroll
    for (int j = 0; j < 16; ++j) {
        int idx = j * 256 + (int)threadIdx.x;
        if (idx < len) { d[j] = dst[beg + idx]; s[j] = src[beg + idx]; }
        else d[j] = -1;
    }
#pragma unroll
    for (int j = 0; j < 16; ++j)
        if (d[j] >= 0) atomicAdd(&hcur[d[j] >> 8], 1u);
    __syncthreads();
    unsigned v = (threadIdx.x < NSB) ? hcur[threadIdx.x] : 0u;
    tile[threadIdx.x] = v;
    __syncthreads();
    for (int off = 1; off < 256; off <<= 1) {
        unsigned t = (threadIdx.x >= (unsigned)off) ? tile[threadIdx.x - off] : 0u;
        __syncthreads();
        tile[threadIdx.x] += t;
        __syncthreads();
    }
    if (threadIdx.x < NSB) {
        unsigned excl = tile[threadIdx.x] - v;
        hscan[threadIdx.x] = excl;
        hcur[threadIdx.x] = excl;
    }
    __syncthreads();
#pragma unroll
    for (int j = 0; j < 16; ++j) {
        if (d[j] >= 0) {
            int sb = d[j] >> 8;
            unsigned p = atomicAdd(&hcur[sb], 1u);
            pay[p] = ((unsigned)(d[j] & 255) << 16) | (unsigned)s[j];
            gpos[p] = hbase[sb] + (p - hscan[sb]);
        }
    }
    __syncthreads();
    for (int i = threadIdx.x; i < len; i += 256)
        tmp[gpos[i]] = (int)pay[i];
}

// ---------- pass 2: per-superbucket fine scatter + deg/rowptr/dinv ----------
__global__ __launch_bounds__(256) void k_bin2(const int* __restrict__ tmpA,
                                              const int* __restrict__ bbA,
                                              unsigned short* __restrict__ csrA,
                                              unsigned* __restrict__ degA,
                                              float* __restrict__ dinvA,
                                              int* __restrict__ rpA,
                                              const int* __restrict__ tmpB,
                                              const int* __restrict__ bbB,
                                              unsigned short* __restrict__ csrB,
                                              unsigned* __restrict__ degB,
                                              float* __restrict__ dinvB,
                                              int* __restrict__ rpB, int half) {
    __shared__ unsigned cnt[256];
    __shared__ unsigned scan[256];
    __shared__ unsigned curs[256];
    bool sec = blockIdx.x >= half;
    int sb = sec ? blockIdx.x - half : blockIdx.x;
    const int* tmp = sec ? tmpB : tmpA;
    const int* bb = sec ? bbB : bbA;
    unsigned short* csr = sec ? csrB : csrA;
    unsigned* deg = sec ? degB : degA;
    float* dinv = sec ? dinvB : dinvA;
    int* rp = sec ? rpB : rpA;
    int beg = bb[sb], end = bb[sb + 1];
    cnt[threadIdx.x] = 0u;
    __syncthreads();
    for (int e = beg + (int)threadIdx.x; e < end; e += 256)
        atomicAdd(&cnt[(tmp[e] >> 16) & 255], 1u);
    __syncthreads();
    unsigned v = cnt[threadIdx.x];
    scan[threadIdx.x] = v;
    __syncthreads();
    for (int off = 1; off < 256; off <<= 1) {
        unsigned t = (threadIdx.x >= (unsigned)off) ? scan[threadIdx.x - off] : 0u;
        __syncthreads();
        scan[threadIdx.x] += t;
        __syncthreads();
    }
    unsigned excl = scan[threadIdx.x] - v;
    int n = sb * 256 + (int)threadIdx.x;
    if (n < NN) {
        deg[n] = v;
        rp[n] = beg + (int)excl;
        dinv[n] = rsqrtf((float)(v + 1u));
    }
    curs[threadIdx.x] = (unsigned)beg + excl;
    __syncthreads();
    for (int e = beg + (int)threadIdx.x; e < end; e += 256) {
        int p = tmp[e];
        unsigned pos = atomicAdd(&curs[(p >> 16) & 255], 1u);
        csr[pos] = (unsigned short)(p & 0xFFFF);
    }
}

// ---------- layer-1 GEMM: split-K row-per-lane, LDS reduce, x read once ----------
__global__ __launch_bounds__(256) void k_gemm_in(const float* __restrict__ x,
                                                 const float* __restrict__ W,
                                                 const float* __restrict__ dinvU,
                                                 const float* __restrict__ dinvV,
                                                 unsigned short* __restrict__ hU,
                                                 unsigned short* __restrict__ hV, int N) {
    __shared__ float part[4 * 64 * 33];   // 33 KB, pad 33 -> <=2-way banks
    int lane = threadIdx.x & 63;
    int wv = __builtin_amdgcn_readfirstlane((int)(threadIdx.x >> 6));
    int row = blockIdx.x * 64 + lane;
    float acc[32];
#pragma unroll
    for (int j = 0; j < 32; ++j) acc[j] = 0.f;
    if (row < N) {
        const float4* xr = reinterpret_cast<const float4*>(x + (size_t)row * NIN);
#pragma unroll 4
        for (int i = 0; i < 16; ++i) {
            int k4 = wv * 16 + i;                 // wave-uniform -> scalar W loads
            float4 v = xr[k4];
            const float* Wk = W + k4 * 4 * HID;
#pragma unroll
            for (int j = 0; j < 32; ++j) {
                acc[j] = fmaf(v.x, Wk[j], acc[j]);
                acc[j] = fmaf(v.y, Wk[HID + j], acc[j]);
                acc[j] = fmaf(v.z, Wk[2 * HID + j], acc[j]);
                acc[j] = fmaf(v.w, Wk[3 * HID + j], acc[j]);
            }
        }
    }
    float* pw = part + (wv * 64 + lane) * 33;
#pragma unroll
    for (int j = 0; j < 32; ++j) pw[j] = acc[j];
    __syncthreads();
    int r = threadIdx.x >> 2;
    int c0 = (threadIdx.x & 3) * 8;
    int orow = blockIdx.x * 64 + r;
    if (orow >= N) return;
    float s[8];
#pragma unroll
    for (int i = 0; i < 8; ++i) {
        s[i] = part[(0 * 64 + r) * 33 + c0 + i]
             + part[(1 * 64 + r) * 33 + c0 + i]
             + part[(2 * 64 + r) * 33 + c0 + i]
             + part[(3 * 64 + r) * 33 + c0 + i];
    }
    float du = dinvU[orow], dw = dinvV[orow];
    uint4 wu, wvv;
    wu.x = pack2(s[0] * du, s[1] * du); wu.y = pack2(s[2] * du, s[3] * du);
    wu.z = pack2(s[4] * du, s[5] * du); wu.w = pack2(s[6] * du, s[7] * du);
    wvv.x = pack2(s[0] * dw, s[1] * dw); wvv.y = pack2(s[2] * dw, s[3] * dw);
    wvv.z = pack2(s[4] * dw, s[5] * dw); wvv.w = pack2(s[6] * dw, s[7] * dw);
    *reinterpret_cast<uint4*>(hU + (size_t)orow * HID + c0) = wu;
    *reinterpret_cast<uint4*>(hV + (size_t)orow * HID + c0) = wvv;
}

// ---------- unified pair pull: bf16 gather-sum, unroll-8, dual acc chains ----------
__device__ __forceinline__ void pull_sum(const unsigned short* __restrict__ t,
                                         const unsigned short* __restrict__ csr,
                                         const int* __restrict__ rowptr,
                                         const unsigned* __restrict__ deg,
                                         float* __restrict__ out, int blk, int tid) {
    int node = blk * 32 + tid / 8;
    int q = tid % 8;
    if (node >= NN) return;
    const ushort4* h4 = reinterpret_cast<const ushort4*>(t);
    int beg = rowptr[node];
    int end = beg + (int)deg[node];
    ushort4 sv = h4[(size_t)node * 8 + q];
    float4 acc0, acc1;
    acc0.x = b2f(sv.x); acc0.y = b2f(sv.y); acc0.z = b2f(sv.z); acc0.w = b2f(sv.w);
    acc1.x = 0.f; acc1.y = 0.f; acc1.z = 0.f; acc1.w = 0.f;
    int e = beg;
    for (; e + 8 <= end; e += 8) {
        int s0 = csr[e],     s1 = csr[e + 1], s2 = csr[e + 2], s3 = csr[e + 3];
        int s4 = csr[e + 4], s5 = csr[e + 5], s6 = csr[e + 6], s7 = csr[e + 7];
        ushort4 v0 = h4[(size_t)s0 * 8 + q];
        ushort4 v1 = h4[(size_t)s1 * 8 + q];
        ushort4 v2 = h4[(size_t)s2 * 8 + q];
        ushort4 v3 = h4[(size_t)s3 * 8 + q];
        ushort4 v4 = h4[(size_t)s4 * 8 + q];
        ushort4 v5 = h4[(size_t)s5 * 8 + q];
        ushort4 v6 = h4[(size_t)s6 * 8 + q];
        ushort4 v7 = h4[(size_t)s7 * 8 + q];
        acc0.x += (b2f(v0.x) + b2f(v1.x)) + (b2f(v2.x) + b2f(v3.x));
        acc0.y += (b2f(v0.y) + b2f(v1.y)) + (b2f(v2.y) + b2f(v3.y));
        acc0.z += (b2f(v0.z) + b2f(v1.z)) + (b2f(v2.z) + b2f(v3.z));
        acc0.w += (b2f(v0.w) + b2f(v1.w)) + (b2f(v2.w) + b2f(v3.w));
        acc1.x += (b2f(v4.x) + b2f(v5.x)) + (b2f(v6.x) + b2f(v7.x));
        acc1.y += (b2f(v4.y) + b2f(v5.y)) + (b2f(v6.y) + b2f(v7.y));
        acc1.z += (b2f(v4.z) + b2f(v5.z)) + (b2f(v6.z) + b2f(v7.z));
        acc1.w += (b2f(v4.w) + b2f(v5.w)) + (b2f(v6.w) + b2f(v7.w));
    }
    if (e + 4 <= end) {
        int s0 = csr[e], s1 = csr[e + 1], s2 = csr[e + 2], s3 = csr[e + 3];
        ushort4 v0 = h4[(size_t)s0 * 8 + q];
        ushort4 v1 = h4[(size_t)s1 * 8 + q];
        ushort4 v2 = h4[(size_t)s2 * 8 + q];
        ushort4 v3 = h4[(size_t)s3 * 8 + q];
        acc1.x += (b2f(v0.x) + b2f(v1.x)) + (b2f(v2.x) + b2f(v3.x));
        acc1.y += (b2f(v0.y) + b2f(v1.y)) + (b2f(v2.y) + b2f(v3.y));
        acc1.z += (b2f(v0.z) + b2f(v1.z)) + (b2f(v2.z) + b2f(v3.z));
        acc1.w += (b2f(v0.w) + b2f(v1.w)) + (b2f(v2.w) + b2f(v3.w));
        e += 4;
    }
    for (; e < end; ++e) {
        ushort4 v0 = h4[(size_t)csr[e] * 8 + q];
        acc0.x += b2f(v0.x); acc0.y += b2f(v0.y);
        acc0.z += b2f(v0.z); acc0.w += b2f(v0.w);
    }
    float4 acc;
    acc.x = acc0.x + acc1.x; acc.y = acc0.y + acc1.y;
    acc.z = acc0.z + acc1.z; acc.w = acc0.w + acc1.w;
    *reinterpret_cast<float4*>(out + (size_t)node * HID + q * 4) = acc;
}

__global__ __launch_bounds__(256) void k_pull_pair(
    const unsigned short* __restrict__ tA, const unsigned short* __restrict__ csrA,
    const int* __restrict__ rpA, const unsigned* __restrict__ degA, float* __restrict__ outA,
    const unsigned short* __restrict__ tB, const unsigned short* __restrict__ csrB,
    const int* __restrict__ rpB, const unsigned* __restrict__ degB, float* __restrict__ outB,
    int nblk) {
    int b = blockIdx.x;
    int xcd = b & 7;
    int blk = (b >> 3) * 4 + (xcd & 3);
    if (blk >= nblk) return;
    if (xcd >= 4) pull_sum(tB, csrB, rpB, degB, outB, blk, threadIdx.x);
    else          pull_sum(tA, csrA, rpA, degA, outA, blk, threadIdx.x);
}

// ---------- L1 mix: 8 lanes/node, shfl-group sim, bf16 T out ----------
__global__ __launch_bounds__(256) void k_mix1(const float* __restrict__ Su,
                                              const float* __restrict__ Sv,
                                              const float* __restrict__ dinvU,
                                              const float* __restrict__ dinvV,
                                              const float* __restrict__ bias,
                                              unsigned short* __restrict__ Tu,
                                              unsigned short* __restrict__ Tv) {
    int node = blockIdx.x * 32 + (threadIdx.x >> 3);
    int q = threadIdx.x & 7;
    if (node >= NN) return;
    float4 su = *reinterpret_cast<const float4*>(Su + (size_t)node * HID + 4 * q);
    float4 sv = *reinterpret_cast<const float4*>(Sv + (size_t)node * HID + 4 * q);
    float du = dinvU[node], dw = dinvV[node];
    float a0 = fmaf(su.x, du, bias[4 * q + 0]);
    float a1 = fmaf(su.y, du, bias[4 * q + 1]);
    float a2 = fmaf(su.z, du, bias[4 * q + 2]);
    float a3 = fmaf(su.w, du, bias[4 * q + 3]);
    float b0 = fmaf(sv.x, dw, bias[4 * q + 0]);
    float b1 = fmaf(sv.y, dw, bias[4 * q + 1]);
    float b2 = fmaf(sv.z, dw, bias[4 * q + 2]);
    float b3 = fmaf(sv.w, dw, bias[4 * q + 3]);
    float n1 = a0 * a0 + a1 * a1 + a2 * a2 + a3 * a3;
    float n2 = b0 * b0 + b1 * b1 + b2 * b2 + b3 * b3;
    float dt = a0 * b0 + a1 * b1 + a2 * b2 + a3 * b3;
#pragma unroll
    for (int m = 4; m >= 1; m >>= 1) {
        n1 += __shfl_xor(n1, m);
        n2 += __shfl_xor(n2, m);
        dt += __shfl_xor(dt, m);
    }
    float sim = dt / (fmaxf(sqrtf(n1), EPS) * fmaxf(sqrtf(n2), EPS));
    uint2 mu, mv;
    mu.x = pack2((a0 + b0 * sim) * du, (a1 + b1 * sim) * du);
    mu.y = pack2((a2 + b2 * sim) * du, (a3 + b3 * sim) * du);
    mv.x = pack2((b0 + a0 * sim) * dw, (b1 + a1 * sim) * dw);
    mv.y = pack2((b2 + a2 * sim) * dw, (b3 + a3 * sim) * dw);
    *reinterpret_cast<uint2*>(Tu + (size_t)node * HID + 4 * q) = mu;
    *reinterpret_cast<uint2*>(Tv + (size_t)node * HID + 4 * q) = mv;
}

// ---------- L2 epilogue: 8 lanes/node, LDS W + z, shfl sim, bf16 Pa/Pb ----------
__global__ __launch_bounds__(256) void k_hid_mix_pack(const float* __restrict__ Su,
                                                      const float* __restrict__ Sv,
                                                      const float* __restrict__ W,
                                                      const float* __restrict__ bias,
                                                      const float* __restrict__ dinvU,
                                                      const float* __restrict__ dinvV,
                                                      unsigned short* __restrict__ Pa,
                                                      unsigned short* __restrict__ Pb) {
    __shared__ float Ws[HID * HID];
    __shared__ float zu[32][33];
    __shared__ float zv[32][33];
    int t = threadIdx.x;
    for (int i = t; i < HID * HID; i += 256) Ws[i] = W[i];
    int nb = blockIdx.x * 32;
    int l = t >> 3, q = t & 7;
    int node = nb + l;
    {
        float4 fu = make_float4(0.f, 0.f, 0.f, 0.f), fv = fu;
        if (node < NN) {
            fu = *reinterpret_cast<const float4*>(Su + (size_t)node * HID + 4 * q);
            fv = *reinterpret_cast<const float4*>(Sv + (size_t)node * HID + 4 * q);
        }
        zu[l][4 * q + 0] = fu.x; zu[l][4 * q + 1] = fu.y;
        zu[l][4 * q + 2] = fu.z; zu[l][4 * q + 3] = fu.w;
        zv[l][4 * q + 0] = fv.x; zv[l][4 * q + 1] = fv.y;
        zv[l][4 * q + 2] = fv.z; zv[l][4 * q + 3] = fv.w;
    }
    __syncthreads();
    if (node >= NN) return;
    float a[4] = {0.f, 0.f, 0.f, 0.f};
    float b[4] = {0.f, 0.f, 0.f, 0.f};
#pragma unroll
    for (int k = 0; k < HID; ++k) {
        float zuk = zu[l][k], zvk = zv[l][k];
        const float* Wk = Ws + k * HID + 4 * q;
#pragma unroll
        for (int j = 0; j < 4; ++j) {
            a[j] = fmaf(zuk, Wk[j], a[j]);
            b[j] = fmaf(zvk, Wk[j], b[j]);
        }
    }
    float du = dinvU[node], dw = dinvV[node];
#pragma unroll
    for (int j = 0; j < 4; ++j) {
        a[j] = fmaf(a[j], du, bias[4 * q + j]);
        b[j] = fmaf(b[j], dw, bias[4 * q + j]);
    }
    float n1 = a[0]*a[0] + a[1]*a[1] + a[2]*a[2] + a[3]*a[3];
    float n2 = b[0]*b[0] + b[1]*b[1] + b[2]*b[2] + b[3]*b[3];
    float dt = a[0]*b[0] + a[1]*b[1] + a[2]*b[2] + a[3]*b[3];
#pragma unroll
    for (int m = 4; m >= 1; m >>= 1) {
        n1 += __shfl_xor(n1, m);
        n2 += __shfl_xor(n2, m);
        dt += __shfl_xor(dt, m);
    }
    float sim = dt / (fmaxf(sqrtf(n1), EPS) * fmaxf(sqrtf(n2), EPS));
    uint2 ma, mb;
    ma.x = pack2((a[0] + b[0] * sim) * du, (a[1] + b[1] * sim) * du);
    ma.y = pack2((a[2] + b[2] * sim) * du, (a[3] + b[3] * sim) * du);
    mb.x = pack2((b[0] + a[0] * sim) * du, (b[1] + a[1] * sim) * du);
    mb.y = pack2((b[2] + a[2] * sim) * du, (b[3] + a[3] * sim) * du);
    *reinterpret_cast<uint2*>(Pa + (size_t)node * HID + 4 * q) = ma;
    *reinterpret_cast<uint2*>(Pb + (size_t)node * HID + 4 * q) = mb;
}

// ---------- L3 GEMM: row-per-lane compute, LDS-staged coalesced stores ----------
__global__ __launch_bounds__(512) void k_gemm_out2(const float* __restrict__ Qa,
                                                   const float* __restrict__ Qb,
                                                   const float* __restrict__ dinvU,
                                                   const float* __restrict__ W,
                                                   const float* __restrict__ b,
                                                   float* __restrict__ out, int N) {
    __shared__ float ob[32 * 257];   // 32 rows/phase, pad 257 -> conflict-free
    int lane = threadIdx.x & 63;
    int wv = (int)(threadIdx.x >> 6);
    int view = __builtin_amdgcn_readfirstlane(wv >> 2);       // 0 or 1
    int c0 = __builtin_amdgcn_readfirstlane((wv & 3) * 32);   // col slice
    int row = blockIdx.x * 64 + lane;
    bool active = row < N;
    float a[32];
#pragma unroll
    for (int j = 0; j < 32; ++j) a[j] = 0.f;
    if (active) {
        const float* Q = view ? Qb : Qa;
        const float4* q4 = reinterpret_cast<const float4*>(Q + (size_t)row * HID);
#pragma unroll 2
        for (int k4 = 0; k4 < 8; ++k4) {
            float4 v = q4[k4];
            const float* Wk = W + (k4 * 4) * FOUT + c0;
#pragma unroll
            for (int j = 0; j < 32; ++j) {
                a[j] = fmaf(v.x, Wk[j], a[j]);
                a[j] = fmaf(v.y, Wk[FOUT + j], a[j]);
                a[j] = fmaf(v.z, Wk[2 * FOUT + j], a[j]);
                a[j] = fmaf(v.w, Wk[3 * FOUT + j], a[j]);
            }
        }
    }
    float du = active ? dinvU[row] : 0.f;
    int r32 = lane & 31;
    int hl = lane >> 5;
    for (int p = 0; p < 2; ++p) {
        if (hl == p) {
            int off = r32 * 257 + view * FOUT + c0;
#pragma unroll
            for (int j = 0; j < 32; ++j)
                ob[off + j] = fmaf(a[j], du, b[c0 + j]);
        }
        __syncthreads();
        int rbase = blockIdx.x * 64 + p * 32;
        int nrows = min(32, N - rbase);
        if (nrows > 0) {
            float* obase = out + (size_t)rbase * OSTR;
            int total = nrows * OSTR;
            for (int f = threadIdx.x; f < total; f += 512)
                obase[f] = ob[f + (f >> 8)];
        }
        __syncthreads();
    }
}

// ---------------- host ----------------
extern "C" void kernel_launch(void* const* d_in, const int* in_sizes, int n_in,
                              void* d_out, int out_size, void* d_ws, size_t ws_size,
                              hipStream_t stream) {
    const float* x     = (const float*)d_in[0];
    const int*   ei_u  = (const int*)d_in[1];
    const int*   ei_u2 = (const int*)d_in[2];
    const float* W_in  = (const float*)d_in[3];
    const float* b_in  = (const float*)d_in[4];
    const float* W_hid = (const float*)d_in[5];
    const float* b_hid = (const float*)d_in[6];
    const float* W_out = (const float*)d_in[7];
    const float* b_out = (const float*)d_in[8];
    float* out = (float*)d_out;

    const int* src_u  = ei_u;
    const int* dst_u  = ei_u + NE;
    const int* src_u2 = ei_u2;
    const int* dst_u2 = ei_u2 + NE;

    char* w = (char*)d_ws;
    auto carve = [&](size_t bytes) {
        char* p = w;
        w += (bytes + 255) & ~(size_t)255;
        return p;
    };
    unsigned* hc_u   = (unsigned*)carve((size_t)NCH * NSB * sizeof(unsigned));
    unsigned* hc_u2  = (unsigned*)carve((size_t)NCH * NSB * sizeof(unsigned));
    unsigned* tot_u  = (unsigned*)carve(NSB * sizeof(unsigned));
    unsigned* tot_u2 = (unsigned*)carve(NSB * sizeof(unsigned));
    int*      bb_u   = (int*)carve((NSB + 1) * sizeof(int));
    int*      bb_u2  = (int*)carve((NSB + 1) * sizeof(int));
    unsigned* deg_u  = (unsigned*)carve(NN * sizeof(unsigned));
    unsigned* deg_u2 = (unsigned*)carve(NN * sizeof(unsigned));
    float*    dinv_u  = (float*)carve(NN * sizeof(float));
    float*    dinv_u2 = (float*)carve(NN * sizeof(float));
    int*      rp_u   = (int*)carve(NN * sizeof(int));
    int*      rp_u2  = (int*)carve(NN * sizeof(int));
    unsigned short* csr_u  = (unsigned short*)carve((size_t)NE * sizeof(unsigned short));
    unsigned short* csr_u2 = (unsigned short*)carve((size_t)NE * sizeof(unsigned short));
    unsigned short* hU = (unsigned short*)carve((size_t)NN * HID * sizeof(unsigned short));
    unsigned short* hV = (unsigned short*)carve((size_t)NN * HID * sizeof(unsigned short));
    unsigned short* Tu = (unsigned short*)carve((size_t)NN * HID * sizeof(unsigned short));
    unsigned short* Tv = (unsigned short*)carve((size_t)NN * HID * sizeof(unsigned short));
    unsigned short* Pa = (unsigned short*)carve((size_t)NN * HID * sizeof(unsigned short));
    unsigned short* Pb = (unsigned short*)carve((size_t)NN * HID * sizeof(unsigned short));
    float* Su = (float*)carve((size_t)NN * HID * sizeof(float));
    float* Sv = (float*)carve((size_t)NN * HID * sizeof(float));
    // coarse-bin payload buffers alias Su/Sv (6.4 MB each; used only before layer 1)
    int* tmp_u  = (int*)Su;
    int* tmp_u2 = (int*)Sv;

    const int BLK = 256;
    const int gP32 = (NN + 31) / 32;        // 1563 blocks per view
    const int nPair = ((gP32 + 3) / 4) * 8; // XCD-partitioned pair grid = 3128
    const int gR64 = (NN + 63) / 64;        // 782

    // --- CSR build ---
    k_hist<<<2 * NCH, BLK, 0, stream>>>(dst_u, dst_u2, hc_u, hc_u2, NCH);
    k_cscan<<<2 * NSB, BLK, 0, stream>>>(hc_u, hc_u2, tot_u, tot_u2, NSB);
    k_bscan<<<2, BLK, 0, stream>>>(tot_u, tot_u2, bb_u, bb_u2);
    k_bin1<<<2 * NCH, BLK, 0, stream>>>(src_u, dst_u, hc_u, bb_u, tmp_u,
                                        src_u2, dst_u2, hc_u2, bb_u2, tmp_u2, NCH);
    k_bin2<<<2 * NSB, BLK, 0, stream>>>(tmp_u, bb_u, csr_u, deg_u, dinv_u, rp_u,
                                        tmp_u2, bb_u2, csr_u2, deg_u2, dinv_u2, rp_u2, NSB);

    // --- layer 1 ---
    k_gemm_in<<<gR64, BLK, 0, stream>>>(x, W_in, dinv_u, dinv_u2, hU, hV, NN);
    k_pull_pair<<<nPair, BLK, 0, stream>>>(hU, csr_u, rp_u, deg_u, Su,
                                           hV, csr_u2, rp_u2, deg_u2, Sv, gP32);
    k_mix1<<<gP32, BLK, 0, stream>>>(Su, Sv, dinv_u, dinv_u2, b_in, Tu, Tv);

    // --- layer 2 (aggregate-then-GEMM) ---
    k_pull_pair<<<nPair, BLK, 0, stream>>>(Tu, csr_u, rp_u, deg_u, Su,
                                           Tv, csr_u2, rp_u2, deg_u2, Sv, gP32);
    k_hid_mix_pack<<<gP32, BLK, 0, stream>>>(Su, Sv, W_hid, b_hid, dinv_u, dinv_u2, Pa, Pb);

    // --- layer 3 (both branches on view u) ---
    k_pull_pair<<<nPair, BLK, 0, stream>>>(Pa, csr_u, rp_u, deg_u, Su,
                                           Pb, csr_u, rp_u, deg_u, Sv, gP32);
    k_gemm_out2<<<gR64, 512, 0, stream>>>(Su, Sv, dinv_u, W_out, b_out, out, NN);

    (void)in_sizes; (void)n_in; (void)out_size; (void)ws_size;
}